// Round 14
// baseline (133.176 us; speedup 1.0000x reference)
//
#include <hip/hip_runtime.h>

// MHA: B=2, S=2048, D=1024, H=16, DH=64. f32 in/out, bf16 MFMA internally.
// cvt_kernel:  X and W f32 -> bf16 once.
// proj_kernel: fused Q/K/V = Xbf @ Wbf^T, pure-bf16 global_load_lds ring,
//              counted vmcnt (byte-identical to round 11, ~25us deterministic).
// attn_kernel: REWRITTEN on 32x32x16 MFMA: swapped QK^T (lane owns q=lane&31),
//              in-register P repack via cvt_pk + v_permlane32_swap (no P LDS),
//              per-lane rescale (no bpermute), block = 128 q-rows (tiles 2j,2j+1),
//              CU-level pairing (jj,23-jj) for causal balance.

typedef unsigned short u16;
typedef unsigned int u32;
typedef u16 u16x4 __attribute__((ext_vector_type(4)));
typedef u16 u16x8 __attribute__((ext_vector_type(8)));
typedef u32 u32x4 __attribute__((ext_vector_type(4)));
typedef __bf16 bf16x8 __attribute__((ext_vector_type(8)));
typedef float f32x4 __attribute__((ext_vector_type(4)));
typedef float f32x16 __attribute__((ext_vector_type(16)));

static __device__ __forceinline__ u16 f2bf(float f) {
  unsigned u = __builtin_bit_cast(unsigned, f);
  return (u16)((u + 0x7FFFu + ((u >> 16) & 1u)) >> 16);
}

static __device__ __forceinline__ u32 cvt_pk_bf16(float lo, float hi) {
  u32 r;
  asm("v_cvt_pk_bf16_f32 %0, %1, %2" : "=v"(r) : "v"(lo), "v"(hi));
  return r;
}

static __device__ __forceinline__ u16x8 cvt8(float4 f0, float4 f1) {
  u32x4 v;
  v[0] = cvt_pk_bf16(f0.x, f0.y);
  v[1] = cvt_pk_bf16(f0.z, f0.w);
  v[2] = cvt_pk_bf16(f1.x, f1.y);
  v[3] = cvt_pk_bf16(f1.z, f1.w);
  return __builtin_bit_cast(u16x8, v);
}

static __device__ __forceinline__ f32x4 mfma16(u16x8 a, u16x8 b, f32x4 c) {
  return __builtin_amdgcn_mfma_f32_16x16x32_bf16(
      __builtin_bit_cast(bf16x8, a), __builtin_bit_cast(bf16x8, b), c, 0, 0, 0);
}

static __device__ __forceinline__ f32x16 mfma32(u16x8 a, u16x8 b, f32x16 c) {
  return __builtin_amdgcn_mfma_f32_32x32x16_bf16(
      __builtin_bit_cast(bf16x8, a), __builtin_bit_cast(bf16x8, b), c, 0, 0, 0);
}

// async global->LDS, 16B/lane; LDS dest = wave-uniform base (+ lane*16 by HW)
#define GLOAD16(GSRC, LDST)                                                  \
  __builtin_amdgcn_global_load_lds(                                         \
      (const __attribute__((address_space(1))) unsigned int*)(GSRC),        \
      (__attribute__((address_space(3))) unsigned int*)(LDST), 16, 0, 0)

#define FENCE() asm volatile("" ::: "memory")
#define BARX()                        \
  do {                                \
    __builtin_amdgcn_s_barrier();     \
    FENCE();                          \
  } while (0)

// ---------------------------------------------------------------- f32 -> bf16
__global__ __launch_bounds__(256) void cvt_kernel(
    const float* __restrict__ Xq, const float* __restrict__ Xk,
    const float* __restrict__ Xv, const float* __restrict__ Wq,
    const float* __restrict__ Wk, const float* __restrict__ Wv,
    u16* __restrict__ Xb, u16* __restrict__ Wb) {
  const int y = blockIdx.y;
  const float* src = (y == 0) ? Xq : (y == 1) ? Xk : (y == 2) ? Xv
                   : (y == 3) ? Wq : (y == 4) ? Wk : Wv;
  const size_t nelem = (y < 3) ? (size_t)4 * 1024 * 1024 : (size_t)1024 * 1024;
  u16* dst = (y < 3) ? Xb + (size_t)y * 4 * 1024 * 1024
                     : Wb + (size_t)(y - 3) * 1024 * 1024;
  const size_t i = ((size_t)blockIdx.x * 256 + threadIdx.x) * 8;
  if (i >= nelem) return;
  const float4 f0 = *(const float4*)(src + i);
  const float4 f1 = *(const float4*)(src + i + 4);
  *(u16x8*)(dst + i) = cvt8(f0, f1);
}

// ---------------------------------------------------------------- projections
__global__ __launch_bounds__(256) void proj_kernel(
    const u16* __restrict__ Xbf, const u16* __restrict__ Wbf,
    u16* __restrict__ Qb, u16* __restrict__ Kb, u16* __restrict__ Vt) {
  const int d0 = blockIdx.x;
  const int tid = (d0 & 7) * 96 + (d0 >> 3);
  const int nI = tid % 24, mI = tid / 24;
  const int mode = nI >> 3;        // 0=Q 1=K 2=V
  const int m0 = mI * 128;
  const int n0 = (nI & 7) * 128;

  const u16* __restrict__ X = Xbf + (size_t)mode * (4 * 1024 * 1024);
  const u16* __restrict__ W = Wbf + (size_t)mode * (1024 * 1024);

  __shared__ __align__(16) char As[3][128 * 64];
  __shared__ __align__(16) char Bs[3][128 * 64];

  const int t = threadIdx.x;
  const int lane = t & 63;
  const int w = t >> 6;
  const int wm = w >> 1, wn = w & 1;
  const int lr = lane & 15, lg = lane >> 4;

  const u16* aptr[2];
  const u16* bptr[2];
  int soff[2];
#pragma unroll
  for (int jj = 0; jj < 2; ++jj) {
    const int j = w * 2 + jj;
    const int row = j * 16 + (lane >> 2);
    const int col = (lane & 3) * 8;
    aptr[jj] = X + (size_t)(m0 + row) * 1024 + col;
    bptr[jj] = W + (size_t)(n0 + row) * 1024 + col;
    soff[jj] = j * 1024;
  }

#define ISSUE(T, BUF)                                                \
  do {                                                               \
    _Pragma("unroll") for (int jj = 0; jj < 2; ++jj)                 \
        GLOAD16(aptr[jj] + (size_t)(T) * 32, As[BUF] + soff[jj]);    \
    _Pragma("unroll") for (int jj = 0; jj < 2; ++jj)                 \
        GLOAD16(bptr[jj] + (size_t)(T) * 32, Bs[BUF] + soff[jj]);    \
  } while (0)

  f32x4 acc[4][4] = {};

#define CMP(BUF)                                                              \
  do {                                                                       \
    u16x8 af[4], bfr[4];                                                     \
    _Pragma("unroll") for (int mi = 0; mi < 4; ++mi) {                        \
      const int row = wm * 64 + mi * 16 + lr;                                \
      af[mi] = *(const u16x8*)(As[BUF] + row * 64 + lg * 16);                \
    }                                                                         \
    _Pragma("unroll") for (int ni = 0; ni < 4; ++ni) {                        \
      const int row = wn * 64 + ni * 16 + lr;                                \
      bfr[ni] = *(const u16x8*)(Bs[BUF] + row * 64 + lg * 16);               \
    }                                                                         \
    _Pragma("unroll") for (int mi = 0; mi < 4; ++mi)                          \
        _Pragma("unroll") for (int ni = 0; ni < 4; ++ni)                      \
            acc[mi][ni] = mfma16(af[mi], bfr[ni], acc[mi][ni]);               \
  } while (0)

  ISSUE(0, 0);
  ISSUE(1, 1);
  ISSUE(2, 2);
  asm volatile("s_waitcnt vmcnt(8)" ::: "memory");
  BARX();

  for (int tt = 0; tt < 29; ++tt) {
    CMP(tt % 3);
    asm volatile("s_waitcnt lgkmcnt(0)" ::: "memory");
    BARX();
    ISSUE(tt + 3, tt % 3);
    asm volatile("s_waitcnt vmcnt(8)" ::: "memory");
    BARX();
  }
  CMP(29 % 3);
  asm volatile("s_waitcnt vmcnt(4)" ::: "memory");
  BARX();
  CMP(30 % 3);
  asm volatile("s_waitcnt vmcnt(0)" ::: "memory");
  BARX();
  CMP(31 % 3);
#undef ISSUE
#undef CMP

#pragma unroll
  for (int mi = 0; mi < 4; ++mi) {
    const int sbase = m0 + wm * 64 + mi * 16 + lg * 4;
    const int b_ = sbase >> 11;
    const int s_ = sbase & 2047;
#pragma unroll
    for (int ni = 0; ni < 4; ++ni) {
      const int n = n0 + wn * 64 + ni * 16 + lr;
      const int h_ = n >> 6, dh = n & 63;
      if (mode == 2) {
        u16x4 pk;
        pk[0] = f2bf(acc[mi][ni][0]);
        pk[1] = f2bf(acc[mi][ni][1]);
        pk[2] = f2bf(acc[mi][ni][2]);
        pk[3] = f2bf(acc[mi][ni][3]);
        *(u16x4*)(Vt + ((size_t)((b_ * 16 + h_) * 64 + dh)) * 2048 + s_) = pk;
      } else {
        const float sc = (mode == 0) ? 0.18033688f : 1.0f;
        u16* dst = (mode == 0 ? Qb : Kb) + (size_t)(b_ * 16 + h_) * (2048 * 64) + dh;
#pragma unroll
        for (int r = 0; r < 4; ++r)
          dst[(size_t)(s_ + r) * 64] = f2bf(acc[mi][ni][r] * sc);
      }
    }
  }
}

// ---------------------------------------------------------------- attention
// pack words {0,2}/{1,3} of a 16-kv B-frag chunk from 8 per-lane p values
#define PACK_CHUNK(P, CC, OUTV)                                            \
  do {                                                                     \
    u32 x0 = cvt_pk_bf16(P[8 * (CC) + 0], P[8 * (CC) + 1]);                \
    u32 y0 = cvt_pk_bf16(P[8 * (CC) + 4], P[8 * (CC) + 5]);                \
    u32 x1 = cvt_pk_bf16(P[8 * (CC) + 2], P[8 * (CC) + 3]);                \
    u32 y1 = cvt_pk_bf16(P[8 * (CC) + 6], P[8 * (CC) + 7]);                \
    asm volatile("v_permlane32_swap_b32 %0, %1" : "+v"(x0), "+v"(y0));     \
    asm volatile("v_permlane32_swap_b32 %0, %1" : "+v"(x1), "+v"(y1));     \
    u32x4 _w;                                                              \
    _w[0] = x0; _w[1] = x1; _w[2] = y0; _w[3] = y1;                        \
    OUTV = __builtin_bit_cast(u16x8, _w);                                  \
  } while (0)

__global__ __launch_bounds__(256, 2) void attn_kernel(
    const u16* __restrict__ Qb, const u16* __restrict__ Kb, const u16* __restrict__ Vt,
    const int* __restrict__ pad, float* __restrict__ out) {
  // block = 128 q-rows (q-tiles 2j, 2j+1); nst = 2j+2. CU-resident pair
  // (jj, 23-jj) -> step sums 34 const. All 4 waves own 32 q-rows, never idle.
  const int id = blockIdx.x;
  const int bh = id & 31;
  const int jj = id >> 5;                    // 0..15
  const int j = (jj < 8) ? jj : 23 - jj;     // bijective onto 0..15
  const int qbase = j * 128;
  const int nst = 2 * j + 2;

  const int b = bh >> 4, h = bh & 15;
  const u16* Qh = Qb + (size_t)bh * (2048 * 64);
  const u16* Kh = Kb + (size_t)bh * (2048 * 64);
  const u16* Vh = Vt + (size_t)bh * (64 * 2048);
  const int* padb = pad + b * 2048;

  __shared__ u16 Ks[2][64 * 64];  // [kv][d], 128B rows, XOR-swizzled, dbuf
  __shared__ u16 Vs[2][64 * 64];  // [d][kv], 128B rows, XOR-swizzled, dbuf

  const int t = threadIdx.x, lane = t & 63, w = t >> 6;
  const int l31 = lane & 31, hi = lane >> 5;
  const int sr = t >> 3, scb = t & 7;
  const int qw = qbase + w * 32;   // wave's first q-row
  const int ql = qw + l31;         // lane's q-row (col of all C tiles)
  const int rsw = (l31 & 7) << 4;  // row-XOR for both K and V frag reads

  // Q B-fragments: row=q=lane&31, k-chunk = hi*8 within each d-16 block
  u16x8 qf[4];
#pragma unroll
  for (int kc = 0; kc < 4; ++kc)
    qf[kc] = *(const u16x8*)(Qh + (size_t)ql * 64 + kc * 16 + hi * 8);

  f32x16 acc0 = {}, acc1 = {};     // d-tiles 0/1: row d = dt*32 + crow(r,hi)
  float mrow = -1e4f, lsum = 0.f;  // per-lane (q = lane&31)

  u16x8 kr0, kr1, vr0, vr1;
  const int sb0 = (sr * 128 + scb * 16) ^ ((sr & 7) << 4);
  const int sb1 = ((32 + sr) * 128 + scb * 16) ^ ((sr & 7) << 4);

  kr0 = *(const u16x8*)(Kh + (size_t)sr * 64 + scb * 8);
  kr1 = *(const u16x8*)(Kh + (size_t)(32 + sr) * 64 + scb * 8);
  vr0 = *(const u16x8*)(Vh + (size_t)sr * 2048 + scb * 8);
  vr1 = *(const u16x8*)(Vh + (size_t)(32 + sr) * 2048 + scb * 8);
  *(u16x8*)((char*)Ks[0] + sb0) = kr0;
  *(u16x8*)((char*)Ks[0] + sb1) = kr1;
  *(u16x8*)((char*)Vs[0] + sb0) = vr0;
  *(u16x8*)((char*)Vs[0] + sb1) = vr1;
  __syncthreads();

  int cur = 0;
  for (int st = 0; st < nst; ++st) {
    const int kv0 = st << 6;
    const bool more = st + 1 < nst;
    if (more) {  // prefetch next K/V tile into regs; written after compute
      const int nv0 = kv0 + 64;
      kr0 = *(const u16x8*)(Kh + (size_t)(nv0 + sr) * 64 + scb * 8);
      kr1 = *(const u16x8*)(Kh + (size_t)(nv0 + 32 + sr) * 64 + scb * 8);
      vr0 = *(const u16x8*)(Vh + (size_t)sr * 2048 + nv0 + scb * 8);
      vr1 = *(const u16x8*)(Vh + (size_t)(32 + sr) * 2048 + nv0 + scb * 8);
    }

    const bool act0 = kv0 <= qw + 31;        // wave-uniform
    const bool act1 = kv0 + 32 <= qw + 31;
    if (act0) {
      const u16* KsC = Ks[cur];
      const u16* VsC = Vs[cur];

      // pad: lane needs kv = kv0 + kvt*32 + 8m + 4hi + e  -> int4 per (kvt,m)
      int4 pv0[4], pv1[4];
#pragma unroll
      for (int m = 0; m < 4; ++m)
        pv0[m] = *(const int4*)(padb + kv0 + 8 * m + 4 * hi);
      int pall = pv0[0].x & pv0[0].y & pv0[0].z & pv0[0].w &
                 pv0[1].x & pv0[1].y & pv0[1].z & pv0[1].w &
                 pv0[2].x & pv0[2].y & pv0[2].z & pv0[2].w &
                 pv0[3].x & pv0[3].y & pv0[3].z & pv0[3].w;
      if (act1) {
#pragma unroll
        for (int m = 0; m < 4; ++m)
          pv1[m] = *(const int4*)(padb + kv0 + 32 + 8 * m + 4 * hi);
        pall &= pv1[0].x & pv1[0].y & pv1[0].z & pv1[0].w &
                pv1[1].x & pv1[1].y & pv1[1].z & pv1[1].w &
                pv1[2].x & pv1[2].y & pv1[2].z & pv1[2].w &
                pv1[3].x & pv1[3].y & pv1[3].z & pv1[3].w;
      }
      const bool fast = (kv0 + 63 <= qw) && __all(pall != 0);

      // ---- QK^T: mfma(K, Q) -> C col = q = lane&31, row = kv crow(r,hi)
      f32x16 s0 = {}, s1 = {};
      __builtin_amdgcn_s_setprio(1);
#pragma unroll
      for (int kc = 0; kc < 4; ++kc) {
        const int koff = kc * 32 + hi * 16;  // byte offset of d-chunk in row
        const u16x8 kf0 = *(const u16x8*)((char*)KsC + ((l31 * 128 + koff) ^ rsw));
        s0 = mfma32(kf0, qf[kc], s0);
        if (act1) {
          const u16x8 kf1 =
              *(const u16x8*)((char*)KsC + (((32 + l31) * 128 + koff) ^ rsw));
          s1 = mfma32(kf1, qf[kc], s1);
        }
      }
      __builtin_amdgcn_s_setprio(0);

      // ---- mask (exactly -1e4 like reference)
      float vv0[16], vv1[16];
      if (fast) {
#pragma unroll
        for (int r = 0; r < 16; ++r) {
          vv0[r] = s0[r];
          vv1[r] = s1[r];
        }
      } else {
        const int thr0 = ql - kv0 - 4 * hi;  // keep if 8m+e <= thr
        const int thr1 = thr0 - 32;
#pragma unroll
        for (int m = 0; m < 4; ++m) {
          const int* pp0 = (const int*)&pv0[m];
#pragma unroll
          for (int e = 0; e < 4; ++e)
            vv0[4 * m + e] =
                (pp0[e] && (8 * m + e) <= thr0) ? s0[4 * m + e] : -1e4f;
        }
        if (act1) {
#pragma unroll
          for (int m = 0; m < 4; ++m) {
            const int* pp1 = (const int*)&pv1[m];
#pragma unroll
            for (int e = 0; e < 4; ++e)
              vv1[4 * m + e] =
                  (pp1[e] && (8 * m + e) <= thr1) ? s1[4 * m + e] : -1e4f;
          }
        }
      }

      // ---- online softmax: per-lane, ONE shfl level (partner = lane^32)
      float mx = vv0[0];
#pragma unroll
      for (int r = 1; r < 16; ++r) mx = fmaxf(mx, vv0[r]);
      if (act1) {
#pragma unroll
        for (int r = 0; r < 16; ++r) mx = fmaxf(mx, vv1[r]);
      }
      mx = fmaxf(mx, __shfl_xor(mx, 32));

      if (!__all(mx <= mrow + 8.0f)) {  // defer-max rescale (per-lane!)
        const float mn = fmaxf(mrow, mx);
        const float al = exp2f(mrow - mn);
        mrow = mn;
        lsum *= al;
        acc0 *= al;
        acc1 *= al;
      }

      float p0[16], p1[16];
      float ps = 0.f;
#pragma unroll
      for (int r = 0; r < 16; ++r) {
        p0[r] = exp2f(vv0[r] - mrow);
        ps += p0[r];
      }
      if (act1) {
#pragma unroll
        for (int r = 0; r < 16; ++r) {
          p1[r] = exp2f(vv1[r] - mrow);
          ps += p1[r];
        }
      }
      ps += __shfl_xor(ps, 32);
      lsum += ps;

      // ---- PV: mfma(V^T, P) -> C col = q, row = d. P repacked in-register.
      __builtin_amdgcn_s_setprio(1);
#pragma unroll
      for (int c = 0; c < 4; ++c) {  // kv 16-chunks; kvt = c>>1
        if (c >= 2 && !act1) continue;
        u16x8 pb;
        if (c == 0) PACK_CHUNK(p0, 0, pb);
        else if (c == 1) PACK_CHUNK(p0, 1, pb);
        else if (c == 2) PACK_CHUNK(p1, 0, pb);
        else PACK_CHUNK(p1, 1, pb);
        const int kvoff = c * 32 + hi * 16;  // byte offset of kv-chunk in row
        const u16x8 vf0 =
            *(const u16x8*)((char*)VsC + ((l31 * 128 + kvoff) ^ rsw));
        const u16x8 vf1 =
            *(const u16x8*)((char*)VsC + (((32 + l31) * 128 + kvoff) ^ rsw));
        acc0 = mfma32(vf0, pb, acc0);
        acc1 = mfma32(vf1, pb, acc1);
      }
      __builtin_amdgcn_s_setprio(0);
    }

    if (more) {  // write-late into the other buffer
      u16* Kn = Ks[cur ^ 1];
      u16* Vn = Vs[cur ^ 1];
      *(u16x8*)((char*)Kn + sb0) = kr0;
      *(u16x8*)((char*)Kn + sb1) = kr1;
      *(u16x8*)((char*)Vn + sb0) = vr0;
      *(u16x8*)((char*)Vn + sb1) = vr1;
    }
    __syncthreads();
    cur ^= 1;
  }

  // ---- epilogue: out[b][ql][h*64 + dt*32 + 8m + 4hi + e] = acc/lsum
  const float il = 1.0f / lsum;
  float* orow = out + ((size_t)(b * 2048 + ql)) * 1024 + h * 64 + 4 * hi;
#pragma unroll
  for (int m = 0; m < 4; ++m) {
    float4 v0, v1;
    v0.x = acc0[4 * m + 0] * il;
    v0.y = acc0[4 * m + 1] * il;
    v0.z = acc0[4 * m + 2] * il;
    v0.w = acc0[4 * m + 3] * il;
    v1.x = acc1[4 * m + 0] * il;
    v1.y = acc1[4 * m + 1] * il;
    v1.z = acc1[4 * m + 2] * il;
    v1.w = acc1[4 * m + 3] * il;
    *(float4*)(orow + 8 * m) = v0;
    *(float4*)(orow + 32 + 8 * m) = v1;
  }
}

extern "C" void kernel_launch(void* const* d_in, const int* in_sizes, int n_in,
                              void* d_out, int out_size, void* d_ws, size_t ws_size,
                              hipStream_t stream) {
  const float* q  = (const float*)d_in[0];
  const float* k  = (const float*)d_in[1];
  const float* v  = (const float*)d_in[2];
  const float* wq = (const float*)d_in[3];
  const float* wk = (const float*)d_in[4];
  const float* wv = (const float*)d_in[5];
  const int* pad  = (const int*)d_in[6];
  float* out = (float*)d_out;

  u16* Qb  = (u16*)d_ws;                     // [B,H,S,64] bf16, pre-scaled (8MB)
  u16* Kb  = Qb + (size_t)4 * 1024 * 1024;   // [B,H,S,64] bf16 (8MB)
  u16* Vt  = Kb + (size_t)4 * 1024 * 1024;   // [B,H,64,S] bf16 (8MB)
  u16* Wbf = Vt + (size_t)4 * 1024 * 1024;   // [3][1024][1024] bf16 (6MB)
  u16* Xbf = Wbf + (size_t)3 * 1024 * 1024;  // [3][B*S][1024] bf16 (24MB)

  dim3 gv(2048, 6);
  cvt_kernel<<<gv, 256, 0, stream>>>(q, k, v, wq, wk, wv, Xbf, Wbf);

  proj_kernel<<<768, 256, 0, stream>>>(Xbf, Wbf, Qb, Kb, Vt);

  attn_kernel<<<512, 256, 0, stream>>>(Qb, Kb, Vt, pad, out);
}